// Round 1
// baseline (915.782 us; speedup 1.0000x reference)
//
#include <hip/hip_runtime.h>
#include <hip/hip_bf16.h>

#define B_SAMP 16384
#define NFEAT 26
#define VOCAB 100000
#define DIM 64
#define NDENSE 13
#define H1 1024
#define H2 512
#define H3 256
#define KIN ((NFEAT + 1) * DIM)   // 1728

typedef short s16x8 __attribute__((ext_vector_type(8)));
typedef float f32x4 __attribute__((ext_vector_type(4)));

// ---------------------------------------------------------------- async 16B
__device__ inline void async_load16(const void* g, void* lds) {
  __builtin_amdgcn_global_load_lds(
      (const __attribute__((address_space(1))) void*)g,
      (__attribute__((address_space(3))) void*)lds, 16, 0, 0);
}

// ------------------------------------------------- embedding + FM + first
// one wave per sample; lane = embedding dim d (D=64 exactly one wave)
__global__ __launch_bounds__(256) void k_embed_fm(
    const float* __restrict__ dense, const int* __restrict__ sidx,
    const float* __restrict__ emb, const float* __restrict__ lin,
    const float* __restrict__ Wd, const float* __restrict__ Wld,
    const float* __restrict__ bld,
    __hip_bfloat16* __restrict__ h, float* __restrict__ partial)
{
  int wave = threadIdx.x >> 6, lane = threadIdx.x & 63;
  int b = blockIdx.x * 4 + wave;
  const float* drow = dense + b * NDENSE;

  // dense embedding: dense[b,:] @ Wd  (ND=13, broadcast loads)
  float de = 0.f;
#pragma unroll
  for (int nd = 0; nd < NDENSE; ++nd) de += drow[nd] * Wd[nd * DIM + lane];

  __hip_bfloat16* hrow = h + (size_t)b * KIN;
  hrow[lane] = __float2bfloat16(de);
  float sum_e = de, sumsq = de * de;

  float fo = 0.f;
  if (lane < NDENSE) fo = drow[lane] * Wld[lane];

  const int* irow = sidx + b * NFEAT;
#pragma unroll
  for (int f = 0; f < NFEAT; ++f) {
    int ix = irow[f];                       // broadcast load
    float e = emb[((size_t)f * VOCAB + ix) * DIM + lane];  // coalesced 256B row
    sum_e += e; sumsq += e * e;
    hrow[(f + 1) * DIM + lane] = __float2bfloat16(e);
  }
  if (lane < NFEAT) fo += lin[(size_t)lane * VOCAB + irow[lane]];

  float sec = sum_e * sum_e - sumsq;
#pragma unroll
  for (int o = 32; o > 0; o >>= 1) {
    sec += __shfl_down(sec, o);
    fo  += __shfl_down(fo, o);
  }
  if (lane == 0) partial[b] = fo + bld[0] + 0.5f * sec;
}

// ------------------------------------------- transpose fp32 [R][C] -> bf16 [C][R]
__global__ __launch_bounds__(256) void k_transpose_bf16(
    const float* __restrict__ src, __hip_bfloat16* __restrict__ dst, int R, int C)
{
  __shared__ float tile[32][33];
  int c0 = blockIdx.x * 32, r0 = blockIdx.y * 32;
  int tx = threadIdx.x & 31, ty = threadIdx.x >> 5;   // 32 x 8
#pragma unroll
  for (int i = 0; i < 32; i += 8)
    tile[ty + i][tx] = src[(size_t)(r0 + ty + i) * C + c0 + tx];
  __syncthreads();
#pragma unroll
  for (int i = 0; i < 32; i += 8)
    dst[(size_t)(c0 + ty + i) * R + r0 + tx] = __float2bfloat16(tile[tx][ty + i]);
}

__global__ void k_conv_bf16(const float* __restrict__ src,
                            __hip_bfloat16* __restrict__ dst, int n) {
  int i = blockIdx.x * blockDim.x + threadIdx.x;
  if (i < n) dst[i] = __float2bfloat16(src[i]);
}

// ----------------------------------------------------------- GEMM (m97 style)
// C[M][N] = A[M][K] * Bt[N][K]^T, optional ReLU, bf16 in/out, fp32 accum.
// 128x128 block tile, BK=32, 4 waves in 2x2, 4x4 16x16x32 MFMAs per wave.
template <bool RELU>
__global__ __launch_bounds__(256) void k_gemm_bt(
    const __hip_bfloat16* __restrict__ A,
    const __hip_bfloat16* __restrict__ Bt,
    __hip_bfloat16* __restrict__ C,
    int M, int N, int K)
{
  __shared__ __hip_bfloat16 As[128 * 32];
  __shared__ __hip_bfloat16 Bs[128 * 32];
  int tid = threadIdx.x;
  int wave = tid >> 6, lane = tid & 63;
  int wm = wave & 1, wn = wave >> 1;
  int bm = blockIdx.x * 128, bn = blockIdx.y * 128;
  int quad = lane >> 4, l15 = lane & 15;
  int srow = lane >> 2;            // 0..15: row within a wave's 16-row chunk
  int schunk = (lane & 3) * 8;     // 0/8/16/24: bf16 elems = lane*16B in LDS

  f32x4 acc[4][4];
#pragma unroll
  for (int i = 0; i < 4; ++i)
#pragma unroll
    for (int j = 0; j < 4; ++j) acc[i][j] = (f32x4){0.f, 0.f, 0.f, 0.f};

  int nk = K >> 5;
  for (int kt = 0; kt < nk; ++kt) {
    int k0 = kt << 5;
    __syncthreads();   // prev iter's LDS reads done before overwrite
#pragma unroll
    for (int i = 0; i < 2; ++i) {
      int row = 64 * i + 16 * wave;                 // wave-uniform LDS base row
      async_load16(A  + (size_t)(bm + row + srow) * K + k0 + schunk,
                   &As[row * 32]);
      async_load16(Bt + (size_t)(bn + row + srow) * K + k0 + schunk,
                   &Bs[row * 32]);
    }
    __syncthreads();   // compiler drains vmcnt before barrier

    s16x8 af[4], bf[4];
#pragma unroll
    for (int i = 0; i < 4; ++i) {
      af[i] = *(const s16x8*)&As[(64 * wm + 16 * i + l15) * 32 + quad * 8];
      bf[i] = *(const s16x8*)&Bs[(64 * wn + 16 * i + l15) * 32 + quad * 8];
    }
#pragma unroll
    for (int mi = 0; mi < 4; ++mi)
#pragma unroll
      for (int ni = 0; ni < 4; ++ni)
        acc[mi][ni] = __builtin_amdgcn_mfma_f32_16x16x32_bf16(
            af[mi], bf[ni], acc[mi][ni], 0, 0, 0);
  }

  // epilogue: C/D layout col = lane&15, row = quad*4 + reg
#pragma unroll
  for (int mi = 0; mi < 4; ++mi)
#pragma unroll
    for (int ni = 0; ni < 4; ++ni)
#pragma unroll
      for (int r = 0; r < 4; ++r) {
        int m = bm + 64 * wm + 16 * mi + quad * 4 + r;
        int n = bn + 64 * wn + 16 * ni + l15;
        float v = acc[mi][ni][r];
        if (RELU) v = fmaxf(v, 0.f);
        C[(size_t)m * N + n] = __float2bfloat16(v);
      }
}

// --------------------------------------------------- final: a3 . Wout + rest
__global__ __launch_bounds__(256) void k_final(
    const __hip_bfloat16* __restrict__ a3, const __hip_bfloat16* __restrict__ wo,
    const float* __restrict__ partial, const float* __restrict__ bias,
    float* __restrict__ out)
{
  int wave = threadIdx.x >> 6, lane = threadIdx.x & 63;
  int b = blockIdx.x * 4 + wave;
  const __hip_bfloat16* row = a3 + (size_t)b * H3;
  float s = 0.f;
#pragma unroll
  for (int i = 0; i < H3 / 64; ++i)
    s += __bfloat162float(row[lane + 64 * i]) * __bfloat162float(wo[lane + 64 * i]);
#pragma unroll
  for (int o = 32; o > 0; o >>= 1) s += __shfl_down(s, o);
  if (lane == 0) out[b] = bias[0] + partial[b] + s;
}

// ---------------------------------------------------------------------------
extern "C" void kernel_launch(void* const* d_in, const int* in_sizes, int n_in,
                              void* d_out, int out_size, void* d_ws, size_t ws_size,
                              hipStream_t stream) {
  const float* dense = (const float*)d_in[0];
  const int*   sidx  = (const int*)d_in[1];
  const float* bias  = (const float*)d_in[2];
  const float* emb   = (const float*)d_in[3];
  const float* lin   = (const float*)d_in[4];
  const float* Wd    = (const float*)d_in[5];
  const float* Wld   = (const float*)d_in[6];
  const float* bld   = (const float*)d_in[7];
  const float* W1    = (const float*)d_in[8];
  const float* W2    = (const float*)d_in[9];
  const float* W3    = (const float*)d_in[10];
  const float* Wout  = (const float*)d_in[11];
  float* out = (float*)d_out;

  char* ws = (char*)d_ws;
  // workspace layout (a2/a3 alias dead h region): peak ~91 MB
  const size_t o_h   = 0;                              // B*1728*2 = 56,623,104
  const size_t o_a2  = 0;                              // B*512*2 (h dead by then)
  const size_t o_a3  = 16777216;                       // B*256*2, inside h region
  const size_t o_a1  = 56623104;                       // B*1024*2 = 33,554,432
  const size_t o_w1t = o_a1 + 33554432;                // 1024*1728*2
  const size_t o_w2t = o_w1t + 3538944;                // 512*1024*2
  const size_t o_w3t = o_w2t + 1048576;                // 256*512*2
  const size_t o_wo  = o_w3t + 262144;                 // 256*2
  const size_t o_par = o_wo + 512;                     // B*4

  __hip_bfloat16* h   = (__hip_bfloat16*)(ws + o_h);
  __hip_bfloat16* a1  = (__hip_bfloat16*)(ws + o_a1);
  __hip_bfloat16* a2  = (__hip_bfloat16*)(ws + o_a2);
  __hip_bfloat16* a3  = (__hip_bfloat16*)(ws + o_a3);
  __hip_bfloat16* W1t = (__hip_bfloat16*)(ws + o_w1t);
  __hip_bfloat16* W2t = (__hip_bfloat16*)(ws + o_w2t);
  __hip_bfloat16* W3t = (__hip_bfloat16*)(ws + o_w3t);
  __hip_bfloat16* Wob = (__hip_bfloat16*)(ws + o_wo);
  float* partial      = (float*)(ws + o_par);

  // weight prep (tiny; runs every call — same work each call)
  k_transpose_bf16<<<dim3(H1 / 32, KIN / 32), 256, 0, stream>>>(W1, W1t, KIN, H1);
  k_transpose_bf16<<<dim3(H2 / 32, H1 / 32), 256, 0, stream>>>(W2, W2t, H1, H2);
  k_transpose_bf16<<<dim3(H3 / 32, H2 / 32), 256, 0, stream>>>(W3, W3t, H2, H3);
  k_conv_bf16<<<1, 256, 0, stream>>>(Wout, Wob, H3);

  // gather + FM + first-order + h materialization
  k_embed_fm<<<B_SAMP / 4, 256, 0, stream>>>(dense, sidx, emb, lin, Wd, Wld, bld,
                                             h, partial);

  // MLP
  k_gemm_bt<true><<<dim3(B_SAMP / 128, H1 / 128), 256, 0, stream>>>(h,  W1t, a1, B_SAMP, H1, KIN);
  k_gemm_bt<true><<<dim3(B_SAMP / 128, H2 / 128), 256, 0, stream>>>(a1, W2t, a2, B_SAMP, H2, H1);
  k_gemm_bt<true><<<dim3(B_SAMP / 128, H3 / 128), 256, 0, stream>>>(a2, W3t, a3, B_SAMP, H3, H1 / 2);

  // combine
  k_final<<<B_SAMP / 4, 256, 0, stream>>>(a3, Wob, partial, bias, out);
}

// Round 2
// 861.005 us; speedup vs baseline: 1.0636x; 1.0636x over previous
//
#include <hip/hip_runtime.h>
#include <hip/hip_bf16.h>

#define B_SAMP 16384
#define NFEAT 26
#define VOCAB 100000
#define DIM 64
#define NDENSE 13
#define H1 1024
#define H2 512
#define H3 256
#define KIN ((NFEAT + 1) * DIM)   // 1728
#define KP1 1792                  // KIN padded to multiple of 128

typedef int   i32x4 __attribute__((ext_vector_type(4)));
typedef int   i32x8 __attribute__((ext_vector_type(8)));
typedef float f32x4 __attribute__((ext_vector_type(4)));

// ---------------------------------------------------------------- helpers
__device__ inline void async_load16(const void* g, void* lds) {
  __builtin_amdgcn_global_load_lds(
      (const __attribute__((address_space(1))) void*)g,
      (__attribute__((address_space(3))) void*)lds, 16, 0, 0);
}

__device__ inline unsigned char f32_to_fp8(float v) {
  // gfx950: OCP e4m3fn, RNE, denorm-capable HW convert
  return (unsigned char)(__builtin_amdgcn_cvt_pk_fp8_f32(v, v, 0, false) & 0xff);
}

// ------------------------------------------------- embedding + FM + first
// one wave per sample; lane = embedding dim d (D=64 exactly one wave)
__global__ __launch_bounds__(256) void k_embed_fm(
    const float* __restrict__ dense, const int* __restrict__ sidx,
    const float* __restrict__ emb, const float* __restrict__ lin,
    const float* __restrict__ Wd, const float* __restrict__ Wld,
    const float* __restrict__ bld,
    unsigned char* __restrict__ h, float* __restrict__ partial)
{
  int wave = threadIdx.x >> 6, lane = threadIdx.x & 63;
  int b = blockIdx.x * 4 + wave;
  const float* drow = dense + b * NDENSE;

  float de = 0.f;
#pragma unroll
  for (int nd = 0; nd < NDENSE; ++nd) de += drow[nd] * Wd[nd * DIM + lane];

  unsigned char* hrow = h + (size_t)b * KP1;
  hrow[lane] = f32_to_fp8(de);
  hrow[KIN + lane] = 0;                    // zero the 64-col K pad
  float sum_e = de, sumsq = de * de;

  float fo = 0.f;
  if (lane < NDENSE) fo = drow[lane] * Wld[lane];

  const int* irow = sidx + b * NFEAT;
#pragma unroll
  for (int f = 0; f < NFEAT; ++f) {
    int ix = irow[f];                                      // broadcast load
    float e = emb[((size_t)f * VOCAB + ix) * DIM + lane];  // coalesced 256B row
    sum_e += e; sumsq += e * e;
    hrow[(f + 1) * DIM + lane] = f32_to_fp8(e);
  }
  if (lane < NFEAT) fo += lin[(size_t)lane * VOCAB + irow[lane]];

  float sec = sum_e * sum_e - sumsq;
#pragma unroll
  for (int o = 32; o > 0; o >>= 1) {
    sec += __shfl_down(sec, o);
    fo  += __shfl_down(fo, o);
  }
  if (lane == 0) partial[b] = fo + bld[0] + 0.5f * sec;
}

// --------------------- transpose fp32 [R][C] -> fp8 [C][Rp], zero-pad r>=R
__global__ __launch_bounds__(256) void k_transpose_fp8(
    const float* __restrict__ src, unsigned char* __restrict__ dst,
    int R, int C, int Rp)
{
  __shared__ float tile[32][33];
  int c0 = blockIdx.x * 32, r0 = blockIdx.y * 32;
  int tx = threadIdx.x & 31, ty = threadIdx.x >> 5;   // 32 x 8
#pragma unroll
  for (int i = 0; i < 32; i += 8) {
    int r = r0 + ty + i;
    tile[ty + i][tx] = (r < R) ? src[(size_t)r * C + c0 + tx] : 0.f;
  }
  __syncthreads();
#pragma unroll
  for (int i = 0; i < 32; i += 8)
    dst[(size_t)(c0 + ty + i) * Rp + r0 + tx] = f32_to_fp8(tile[tx][ty + i]);
}

// ----------------------------------------------------- MX-fp8 GEMM (scale=1)
// C[M][N] = A[M][K] * Bt[N][K]^T, fp8 e4m3 in, fp32 accum, K%128==0.
// 128x128 block tile, BK=128, 4 waves 2x2, 4x4 of 16x16x128 MFMAs per wave.
// LDS layout per 16-row subtile (2048 B): [chunk j=0,1][lane 0..63][16 B]
// where lane l <-> (row=l&15, kquad=l>>4); matches global_load_lds's
// wave-uniform-base + lane*16 scatter AND gives linear conflict-free
// ds_read_b128 at frag time.
template <bool RELU, bool FP8OUT>
__global__ __launch_bounds__(256) void k_gemm_fp8(
    const unsigned char* __restrict__ A,
    const unsigned char* __restrict__ Bt,
    void* __restrict__ Cv, int M, int N, int K)
{
  __shared__ unsigned char As[16384];
  __shared__ unsigned char Bs[16384];
  int tid = threadIdx.x;
  int wave = tid >> 6, lane = tid & 63;
  int wm = wave & 1, wn = wave >> 1;
  int bm = blockIdx.x * 128, bn = blockIdx.y * 128;
  int l15 = lane & 15, quad = lane >> 4;

  f32x4 acc[4][4];
#pragma unroll
  for (int i = 0; i < 4; ++i)
#pragma unroll
    for (int j = 0; j < 4; ++j) acc[i][j] = (f32x4){0.f, 0.f, 0.f, 0.f};

  int nk = K >> 7;
  for (int kt = 0; kt < nk; ++kt) {
    int k0 = kt << 7;
    __syncthreads();
#pragma unroll
    for (int s = 0; s < 2; ++s) {
      int st = 2 * wave + s;                                // subtile 0..7
      size_t ga = (size_t)(bm + st * 16 + l15) * K + k0 + quad * 32;
      size_t gb = (size_t)(bn + st * 16 + l15) * K + k0 + quad * 32;
#pragma unroll
      for (int j = 0; j < 2; ++j) {
        async_load16(A + ga + j * 16, &As[st * 2048 + j * 1024]);
        async_load16(Bt + gb + j * 16, &Bs[st * 2048 + j * 1024]);
      }
    }
    __syncthreads();

    i32x8 af[4], bf[4];
#pragma unroll
    for (int i = 0; i < 4; ++i) {
      {
        i32x4 lo = *(const i32x4*)&As[(4 * wm + i) * 2048 + lane * 16];
        i32x4 hi = *(const i32x4*)&As[(4 * wm + i) * 2048 + 1024 + lane * 16];
        af[i] = (i32x8){lo.x, lo.y, lo.z, lo.w, hi.x, hi.y, hi.z, hi.w};
      }
      {
        i32x4 lo = *(const i32x4*)&Bs[(4 * wn + i) * 2048 + lane * 16];
        i32x4 hi = *(const i32x4*)&Bs[(4 * wn + i) * 2048 + 1024 + lane * 16];
        bf[i] = (i32x8){lo.x, lo.y, lo.z, lo.w, hi.x, hi.y, hi.z, hi.w};
      }
    }
#pragma unroll
    for (int mi = 0; mi < 4; ++mi)
#pragma unroll
      for (int ni = 0; ni < 4; ++ni)
        acc[mi][ni] = __builtin_amdgcn_mfma_scale_f32_16x16x128_f8f6f4(
            af[mi], bf[ni], acc[mi][ni],
            0 /*fp8 A*/, 0 /*fp8 B*/, 0, 0x7f7f7f7f, 0, 0x7f7f7f7f);
  }

  // epilogue: C/D layout (shape-determined): col = lane&15, row = quad*4 + r
#pragma unroll
  for (int mi = 0; mi < 4; ++mi)
#pragma unroll
    for (int ni = 0; ni < 4; ++ni)
#pragma unroll
      for (int r = 0; r < 4; ++r) {
        int m = bm + 64 * wm + 16 * mi + quad * 4 + r;
        int n = bn + 64 * wn + 16 * ni + l15;
        float v = acc[mi][ni][r];
        if (RELU) v = fmaxf(v, 0.f);
        if (FP8OUT) ((unsigned char*)Cv)[(size_t)m * N + n] = f32_to_fp8(v);
        else        ((float*)Cv)[(size_t)m * N + n] = v;
      }
}

// --------------------------------------------------- final: a3 . Wout + rest
__global__ __launch_bounds__(256) void k_final(
    const float* __restrict__ a3, const float* __restrict__ wo,
    const float* __restrict__ partial, const float* __restrict__ bias,
    float* __restrict__ out)
{
  int wave = threadIdx.x >> 6, lane = threadIdx.x & 63;
  int b = blockIdx.x * 4 + wave;
  const float* row = a3 + (size_t)b * H3;
  float s = 0.f;
#pragma unroll
  for (int i = 0; i < H3 / 64; ++i)
    s += row[lane + 64 * i] * wo[lane + 64 * i];
#pragma unroll
  for (int o = 32; o > 0; o >>= 1) s += __shfl_down(s, o);
  if (lane == 0) out[b] = bias[0] + partial[b] + s;
}

// ---------------------------------------------------------------------------
extern "C" void kernel_launch(void* const* d_in, const int* in_sizes, int n_in,
                              void* d_out, int out_size, void* d_ws, size_t ws_size,
                              hipStream_t stream) {
  const float* dense = (const float*)d_in[0];
  const int*   sidx  = (const int*)d_in[1];
  const float* bias  = (const float*)d_in[2];
  const float* emb   = (const float*)d_in[3];
  const float* lin   = (const float*)d_in[4];
  const float* Wd    = (const float*)d_in[5];
  const float* Wld   = (const float*)d_in[6];
  const float* bld   = (const float*)d_in[7];
  const float* W1    = (const float*)d_in[8];
  const float* W2    = (const float*)d_in[9];
  const float* W3    = (const float*)d_in[10];
  const float* Wout  = (const float*)d_in[11];
  float* out = (float*)d_out;

  char* ws = (char*)d_ws;
  const size_t o_h   = 0;                      // B*1792   = 29,360,128
  const size_t o_a1  = 29360128;               // B*1024   = 16,777,216
  const size_t o_a2  = 46137344;               // B*512    =  8,388,608
  const size_t o_a3  = 54525952;               // B*256*4  = 16,777,216 (fp32!)
  const size_t o_w1t = 71303168;               // 1024*1792 = 1,835,008
  const size_t o_w2t = 73138176;               // 512*1024  =   524,288
  const size_t o_w3t = 73662464;               // 256*512   =   131,072
  const size_t o_par = 73793536;               // B*4

  unsigned char* h   = (unsigned char*)(ws + o_h);
  unsigned char* a1  = (unsigned char*)(ws + o_a1);
  unsigned char* a2  = (unsigned char*)(ws + o_a2);
  float*         a3  = (float*)(ws + o_a3);
  unsigned char* W1t = (unsigned char*)(ws + o_w1t);
  unsigned char* W2t = (unsigned char*)(ws + o_w2t);
  unsigned char* W3t = (unsigned char*)(ws + o_w3t);
  float* partial     = (float*)(ws + o_par);

  // weight prep: fp32 [K][N] -> fp8 [N][Kp]
  k_transpose_fp8<<<dim3(H1 / 32, KP1 / 32), 256, 0, stream>>>(W1, W1t, KIN, H1, KP1);
  k_transpose_fp8<<<dim3(H2 / 32, H1 / 32), 256, 0, stream>>>(W2, W2t, H1, H2, H1);
  k_transpose_fp8<<<dim3(H3 / 32, H2 / 32), 256, 0, stream>>>(W3, W3t, H2, H3, H2);

  // gather + FM + first-order + fp8 h materialization
  k_embed_fm<<<B_SAMP / 4, 256, 0, stream>>>(dense, sidx, emb, lin, Wd, Wld, bld,
                                             h, partial);

  // MLP, MX-fp8 MFMA (scales = 1.0)
  k_gemm_fp8<true, true ><<<dim3(B_SAMP / 128, H1 / 128), 256, 0, stream>>>(h,  W1t, a1, B_SAMP, H1, KP1);
  k_gemm_fp8<true, true ><<<dim3(B_SAMP / 128, H2 / 128), 256, 0, stream>>>(a1, W2t, a2, B_SAMP, H2, H1);
  k_gemm_fp8<true, false><<<dim3(B_SAMP / 128, H3 / 128), 256, 0, stream>>>(a2, W3t, a3, B_SAMP, H3, H2);

  // combine (a3 and Wout both fp32)
  k_final<<<B_SAMP / 4, 256, 0, stream>>>(a3, Wout, partial, bias, out);
}